// Round 1
// baseline (92.726 us; speedup 1.0000x reference)
//
#include <hip/hip_runtime.h>

#define B_ 128
#define K_ 64
#define IPB 8           // i-values per block in main kernel
#define LDT 68          // padded LDS row stride (17 x 16B -> odd 16B slots, ~conflict-free b128)

// ---------------- Kernel 1: normalized 2D CDFs for student & teacher ----------------
// grid = 2*B blocks (sel 0=student, 1=teacher), 64 threads (1 wave) each.
__global__ __launch_bounds__(64) void emd_cdf_kernel(
    const float* __restrict__ student, const float* __restrict__ teacher,
    float* __restrict__ ws)
{
    __shared__ float tile[K_ * 65];   // [row][col] padded +1
    const int bid = blockIdx.x;       // 0..255
    const int b   = bid & (B_ - 1);
    const int sel = bid >> 7;         // 0 student, 1 teacher
    const float* __restrict__ src = sel ? teacher : student;
    float* __restrict__ dst = ws + (size_t)sel * B_ * K_ * K_ + (size_t)b * K_ * K_;

    const int t = threadIdx.x;        // 0..63

    // Row cumsum: thread t = row r. counts at channel 2 of interleaved [...,3].
    {
        float run = 0.f;
        const size_t base = ((size_t)(b * K_ + t) * K_) * 3 + 2;
        for (int j = 0; j < K_; ++j) {
            run += src[base + (size_t)j * 3];
            tile[t * 65 + j] = run;
        }
    }
    __syncthreads();
    // Column cumsum: thread t = col c.
    {
        float run = 0.f;
        for (int i = 0; i < K_; ++i) {
            run += tile[i * 65 + t];
            tile[i * 65 + t] = run;
        }
    }
    __syncthreads();
    const float total = tile[63 * 65 + 63];       // raw sum over all counts
    const float scale = 1.0f / (total + 1e-6f);   // == normalize-then-cumsum (linearity)
    // Coalesced write-out
    for (int s = 0; s < K_; ++s) {
        dst[s * K_ + t] = tile[s * 65 + t] * scale;
    }
}

// ---------------- Kernel 2: main B*K^3 reduction ----------------
// grid = B * (K/IPB) = 1024 blocks, 256 threads.
// block -> batch b, i in [ic, ic+IPB). thread -> j = t>>2, k-quarter = t&3.
__global__ __launch_bounds__(256) void emd_main_kernel(
    const float* __restrict__ student, const float* __restrict__ teacher,
    const float* __restrict__ ws, float* __restrict__ out)
{
    __shared__ float sTx[K_ * LDT];
    __shared__ float sTy[K_ * LDT];
    __shared__ float sCt[K_ * LDT];
    __shared__ float red[4];

    const int bid = blockIdx.x;
    const int b   = bid >> 3;
    const int ic  = (bid & 7) * IPB;
    const int t   = threadIdx.x;

    const float* __restrict__ cdfP = ws + (size_t)b * K_ * K_;
    const float* __restrict__ cdfT = ws + (size_t)B_ * K_ * K_ + (size_t)b * K_ * K_;

    // Stage teacher bin centers + teacher CDF for this batch into LDS.
    for (int e = t; e < K_ * K_; e += 256) {
        const int j = e >> 6, k = e & 63;
        const size_t te = ((size_t)b * K_ * K_ + e) * 3;
        sTx[j * LDT + k] = teacher[te];
        sTy[j * LDT + k] = teacher[te + 1];
        sCt[j * LDT + k] = cdfT[e];
    }
    __syncthreads();

    const int j  = t >> 2;        // 0..63 : pred col == teacher row
    const int k0 = (t & 3) * 16;  // this thread's k-range start

    // Hoist pred-side values (fixed j, 8 i's) into registers.
    float Px[IPB], Py[IPB], cP[IPB];
    #pragma unroll
    for (int ii = 0; ii < IPB; ++ii) {
        const int i = ic + ii;
        const size_t pe = ((size_t)(b * K_ + i) * K_ + j) * 3;
        Px[ii] = student[pe];
        Py[ii] = student[pe + 1];
        cP[ii] = cdfP[i * K_ + j];
    }

    float acc = 0.f;
    #pragma unroll
    for (int kk = 0; kk < 16; kk += 4) {
        const float4 tx = *(const float4*)&sTx[j * LDT + k0 + kk];
        const float4 ty = *(const float4*)&sTy[j * LDT + k0 + kk];
        const float4 ct = *(const float4*)&sCt[j * LDT + k0 + kk];
        #pragma unroll
        for (int ii = 0; ii < IPB; ++ii) {
            {
                const float dx = Px[ii] - tx.x, dy = Py[ii] - ty.x;
                acc += sqrtf(dx * dx + dy * dy) * fabsf(cP[ii] - ct.x);
            }
            {
                const float dx = Px[ii] - tx.y, dy = Py[ii] - ty.y;
                acc += sqrtf(dx * dx + dy * dy) * fabsf(cP[ii] - ct.y);
            }
            {
                const float dx = Px[ii] - tx.z, dy = Py[ii] - ty.z;
                acc += sqrtf(dx * dx + dy * dy) * fabsf(cP[ii] - ct.z);
            }
            {
                const float dx = Px[ii] - tx.w, dy = Py[ii] - ty.w;
                acc += sqrtf(dx * dx + dy * dy) * fabsf(cP[ii] - ct.w);
            }
        }
    }

    // Reduce: wave shuffle (64 lanes), then cross-wave via LDS, one atomic per block.
    #pragma unroll
    for (int off = 32; off > 0; off >>= 1)
        acc += __shfl_down(acc, off, 64);
    const int wave = t >> 6, lane = t & 63;
    if (lane == 0) red[wave] = acc;
    __syncthreads();
    if (t == 0) {
        const float s = red[0] + red[1] + red[2] + red[3];
        atomicAdd(out, s * (1.0f / (float)(B_ * K_)));
    }
}

extern "C" void kernel_launch(void* const* d_in, const int* in_sizes, int n_in,
                              void* d_out, int out_size, void* d_ws, size_t ws_size,
                              hipStream_t stream) {
    const float* student = (const float*)d_in[0];
    const float* teacher = (const float*)d_in[1];
    float* ws  = (float*)d_ws;     // [2][B][K][K] f32 CDFs = 4 MiB
    float* out = (float*)d_out;

    hipMemsetAsync(d_out, 0, sizeof(float), stream);
    emd_cdf_kernel<<<2 * B_, 64, 0, stream>>>(student, teacher, ws);
    emd_main_kernel<<<B_ * (K_ / IPB), 256, 0, stream>>>(student, teacher, ws, out);
}

// Round 2
// 89.388 us; speedup vs baseline: 1.0373x; 1.0373x over previous
//
#include <hip/hip_runtime.h>

#define B_ 128
#define K_ 64
#define IPB 8           // i-values per block in main kernel
#define LDT 68          // padded LDS row stride for main kernel

// ---------------- Kernel 1: normalized 2D CDFs for student & teacher ----------------
// grid = 2*B blocks (sel 0=student, 1=teacher), 256 threads (4 waves) each.
// Row pass + column pass each done as wave-parallel shuffle prefix scans.
__global__ __launch_bounds__(256) void emd_cdf_kernel(
    const float* __restrict__ student, const float* __restrict__ teacher,
    float* __restrict__ ws, float* __restrict__ out)
{
    __shared__ float tile[K_ * 65];   // [row][col] padded +1 (col-pass bank-conflict-free)
    const int bid = blockIdx.x;       // 0..255
    const int b   = bid & (B_ - 1);
    const int sel = bid >> 7;         // 0 student, 1 teacher
    const float* __restrict__ src = sel ? teacher : student;
    float* __restrict__ dst = ws + (size_t)sel * B_ * K_ * K_ + (size_t)b * K_ * K_;

    const int t    = threadIdx.x;
    const int wave = t >> 6;
    const int lane = t & 63;

    if (bid == 0 && t == 0) out[0] = 0.0f;   // replaces hipMemsetAsync; stream-ordered before main kernel

    // ---- Row pass: wave handles 16 rows; lane = column. Inclusive scan via shfl_up. ----
    #pragma unroll 4
    for (int it = 0; it < 16; ++it) {
        const int r = wave * 16 + it;
        float v = src[((size_t)(b * K_ + r) * K_ + lane) * 3 + 2];
        #pragma unroll
        for (int off = 1; off < 64; off <<= 1) {
            const float u = __shfl_up(v, off, 64);
            if (lane >= off) v += u;
        }
        tile[r * 65 + lane] = v;
    }
    __syncthreads();

    // ---- Column pass: wave handles 16 columns; lane = row. ----
    #pragma unroll 4
    for (int it = 0; it < 16; ++it) {
        const int c = wave * 16 + it;
        float v = tile[lane * 65 + c];        // banks (lane+c)%32 -> 2-way, free
        #pragma unroll
        for (int off = 1; off < 64; off <<= 1) {
            const float u = __shfl_up(v, off, 64);
            if (lane >= off) v += u;
        }
        tile[lane * 65 + c] = v;
    }
    __syncthreads();

    const float total = tile[63 * 65 + 63];       // raw sum of all counts
    const float scale = 1.0f / (total + 1e-6f);   // normalize-then-cumsum == cumsum-then-scale
    #pragma unroll
    for (int it = 0; it < 16; ++it) {
        const int e = t + 256 * it;
        dst[e] = tile[(e >> 6) * 65 + (e & 63)] * scale;
    }
}

// ---------------- Kernel 2: main B*K^3 reduction ----------------
// grid = B * (K/IPB) = 1024 blocks, 256 threads.
// block -> batch b, i in [ic, ic+IPB). thread -> j = t>>2, k-quarter = t&3.
__global__ __launch_bounds__(256) void emd_main_kernel(
    const float* __restrict__ student, const float* __restrict__ teacher,
    const float* __restrict__ ws, float* __restrict__ out)
{
    __shared__ float sTx[K_ * LDT];
    __shared__ float sTy[K_ * LDT];
    __shared__ float sCt[K_ * LDT];
    __shared__ float red[4];

    const int bid = blockIdx.x;
    const int b   = bid >> 3;
    const int ic  = (bid & 7) * IPB;
    const int t   = threadIdx.x;

    const float* __restrict__ cdfP = ws + (size_t)b * K_ * K_;
    const float* __restrict__ cdfT = ws + (size_t)B_ * K_ * K_ + (size_t)b * K_ * K_;

    // Stage teacher bin centers + teacher CDF for this batch into LDS.
    for (int e = t; e < K_ * K_; e += 256) {
        const int j = e >> 6, k = e & 63;
        const size_t te = ((size_t)b * K_ * K_ + e) * 3;
        sTx[j * LDT + k] = teacher[te];
        sTy[j * LDT + k] = teacher[te + 1];
        sCt[j * LDT + k] = cdfT[e];
    }
    __syncthreads();

    const int j  = t >> 2;        // 0..63 : pred col == teacher row
    const int k0 = (t & 3) * 16;  // this thread's k-range start

    // Hoist pred-side values (fixed j, 8 i's) into registers.
    float Px[IPB], Py[IPB], cP[IPB];
    #pragma unroll
    for (int ii = 0; ii < IPB; ++ii) {
        const int i = ic + ii;
        const size_t pe = ((size_t)(b * K_ + i) * K_ + j) * 3;
        Px[ii] = student[pe];
        Py[ii] = student[pe + 1];
        cP[ii] = cdfP[i * K_ + j];
    }

    float acc = 0.f;
    #pragma unroll
    for (int kk = 0; kk < 16; kk += 4) {
        const float4 tx = *(const float4*)&sTx[j * LDT + k0 + kk];
        const float4 ty = *(const float4*)&sTy[j * LDT + k0 + kk];
        const float4 ct = *(const float4*)&sCt[j * LDT + k0 + kk];
        #pragma unroll
        for (int ii = 0; ii < IPB; ++ii) {
            {
                const float dx = Px[ii] - tx.x, dy = Py[ii] - ty.x;
                acc += __builtin_amdgcn_sqrtf(dx * dx + dy * dy) * fabsf(cP[ii] - ct.x);
            }
            {
                const float dx = Px[ii] - tx.y, dy = Py[ii] - ty.y;
                acc += __builtin_amdgcn_sqrtf(dx * dx + dy * dy) * fabsf(cP[ii] - ct.y);
            }
            {
                const float dx = Px[ii] - tx.z, dy = Py[ii] - ty.z;
                acc += __builtin_amdgcn_sqrtf(dx * dx + dy * dy) * fabsf(cP[ii] - ct.z);
            }
            {
                const float dx = Px[ii] - tx.w, dy = Py[ii] - ty.w;
                acc += __builtin_amdgcn_sqrtf(dx * dx + dy * dy) * fabsf(cP[ii] - ct.w);
            }
        }
    }

    // Reduce: wave shuffle (64 lanes), then cross-wave via LDS, one atomic per block.
    #pragma unroll
    for (int off = 32; off > 0; off >>= 1)
        acc += __shfl_down(acc, off, 64);
    const int wave = t >> 6, lane = t & 63;
    if (lane == 0) red[wave] = acc;
    __syncthreads();
    if (t == 0) {
        const float s = red[0] + red[1] + red[2] + red[3];
        atomicAdd(out, s * (1.0f / (float)(B_ * K_)));
    }
}

extern "C" void kernel_launch(void* const* d_in, const int* in_sizes, int n_in,
                              void* d_out, int out_size, void* d_ws, size_t ws_size,
                              hipStream_t stream) {
    const float* student = (const float*)d_in[0];
    const float* teacher = (const float*)d_in[1];
    float* ws  = (float*)d_ws;     // [2][B][K][K] f32 CDFs = 4 MiB
    float* out = (float*)d_out;

    emd_cdf_kernel<<<2 * B_, 256, 0, stream>>>(student, teacher, ws, out);
    emd_main_kernel<<<B_ * (K_ / IPB), 256, 0, stream>>>(student, teacher, ws, out);
}